// Round 16
// baseline (1589.645 us; speedup 1.0000x reference)
//
#include <hip/hip_runtime.h>

constexpr int NN = 500000;
constexpr int NE = 16000000;
constexpr int BN = 512;                       // dst nodes per bucket
constexpr int NBUCK = (NN + BN - 1) / BN;     // 977
constexpr int NSLICE = 8;                     // src slices of 65536 nodes
constexpr int NKEY = NSLICE * BN;             // 4096 sort bins per bucket
constexpr int CAPA = 17408;                   // per-bucket cap: mean 16384, +8 sigma
constexpr int PAIR_CAP = 5120;                // per-pair cap: mean 4094, +16 sigma
constexpr int TILE_A = 16384;                 // edges per pass-A tile (LDS-staged)
constexpr int NTILE_A = (NE + TILE_A - 1) / TILE_A; // 977
constexpr int NB_NODE = (NN + 255) / 256;     // 1954

typedef int int4v __attribute__((ext_vector_type(4)));

// ---------------- bf16 helpers ----------------
__device__ __forceinline__ unsigned bfr(float x) {   // fp32 -> bf16 bits (RNE)
    unsigned u = __float_as_uint(x);
    u += 0x7fffu + ((u >> 16) & 1u);
    return u >> 16;
}
__device__ __forceinline__ float bfl(unsigned u) { return __uint_as_float(u << 16); }
__device__ __forceinline__ float bfh(unsigned u) { return __uint_as_float(u & 0xffff0000u); }

// ---------------- pass A: LDS counting sort per tile, coalesced bucket write-out ----
// R1: scattered 4B stores -> 392 MB WRITE_SIZE. R4: fixed (passA out of top-5).
__global__ void __launch_bounds__(1024, 8) passA(const int* __restrict__ src,
                                                 const int* __restrict__ dst,
                                                 int* __restrict__ gcnt,
                                                 int* __restrict__ storeA) {
    __shared__ int hist[1024];    // per-bucket count (977 used)
    __shared__ int lbase[1024];   // local exclusive scan (bucket start in stage)
    __shared__ int lcur[1024];    // local scatter cursor
    __shared__ int gbase[1024];   // absolute base in storeA
    __shared__ int stage[TILE_A]; // 64 KB sorted tile
    const int tid = threadIdx.x;
    const int base = blockIdx.x * TILE_A;
    const int nt = min(TILE_A, NE - base);
    hist[tid] = 0;
    __syncthreads();
    for (int i = tid; i < nt; i += 1024)
        atomicAdd(&hist[dst[base + i] >> 9], 1);
    __syncthreads();
    const int cnt = hist[tid];
    lbase[tid] = cnt;
    __syncthreads();
    // inclusive Hillis-Steele scan over 1024 bins
    for (int off = 1; off < 1024; off <<= 1) {
        int add = (tid >= off) ? lbase[tid - off] : 0;
        __syncthreads();
        lbase[tid] += add;
        __syncthreads();
    }
    const int lb = lbase[tid] - cnt;   // exclusive
    lcur[tid] = lb;
    if (tid < NBUCK && cnt > 0) {
        int g = atomicAdd(&gcnt[tid], cnt);
        gbase[tid] = tid * CAPA + g;
    }
    __syncthreads();
    lbase[tid] = lb;                   // publish exclusive base for write-out
    // scatter tile into LDS in bucket-sorted order
    for (int i = tid; i < nt; i += 1024) {
        int d = dst[base + i];
        int s = src[base + i];         // tile window L2-hot on re-read
        int p = atomicAdd(&lcur[d >> 9], 1);
        stage[p] = (s << 9) | (d & 511);
    }
    __syncthreads();
    // coalesced write-out: one bucket per wave iteration
    const int wid = tid >> 6, lane = tid & 63;
    for (int b = wid; b < NBUCK; b += 16) {
        int c = hist[b];
        if (c == 0) continue;
        int l0 = lbase[b];
        int g0 = gbase[b];
        int wl = min(c, (b + 1) * CAPA - g0);  // statistically never clips
        for (int j = lane; j < wl; j += 64)
            storeA[g0 + j] = stage[l0 + j];
    }
}

// ---------------- pass B: per-bucket sort by (PAIR, dst, slice-parity) ----------------
// R11 confirmed: (pair,dst,parity) key (~8-edge runs) + pair-phases = best.
// key(e): pair = e>>26, parity = (e>>25)&1, dst = e&511.
__global__ void __launch_bounds__(512) passB(const int* __restrict__ gcnt,
                                             const int* __restrict__ storeA,
                                             int* __restrict__ sortedB,
                                             float* __restrict__ inv,
                                             int* __restrict__ soff) {
    __shared__ int hist[NKEY];    // 16 KB: counts, then (after scan) scatter cursors
    __shared__ int sc[512];       // 2 KB
    __shared__ int stage[CAPA];   // 68 KB sorted bucket
    const int bkt = blockIdx.x;
    const int tid = threadIdx.x;
#pragma unroll
    for (int u = 0; u < NKEY / 512; ++u) hist[tid + u * 512] = 0;
    __syncthreads();
    const int n = min(gcnt[bkt], CAPA);
    const int* bs = storeA + (size_t)bkt * CAPA;
    // histogram (dwordx4 reads; bs is 16B-aligned, tail scalar)
    const int n4 = n & ~3;
    for (int k = tid * 4; k < n4; k += 2048) {
        int4v e4 = *(const int4v*)(bs + k);
#pragma unroll
        for (int u = 0; u < 4; ++u) {
            int e = e4[u];
            int key = ((e >> 26) << 10) | ((e & 511) << 1) | ((e >> 25) & 1);
            atomicAdd(&hist[key], 1);
        }
    }
    for (int k = n4 + tid; k < n; k += 512) {
        int e = bs[k];
        int key = ((e >> 26) << 10) | ((e & 511) << 1) | ((e >> 25) & 1);
        atomicAdd(&hist[key], 1);
    }
    __syncthreads();
    // inv[] from per-dst counts (sum over 4 pairs x 2 parities)
    {
        int node = bkt * BN + tid;
        if (node < NN) {
            int c = 0;
#pragma unroll
            for (int p = 0; p < 4; ++p)
#pragma unroll
                for (int q = 0; q < 2; ++q)
                    c += hist[(p << 10) | (tid << 1) | q];
            inv[node] = 1.0f / fmaxf((float)c, 1.0f);
        }
    }
    // exclusive scan of 4096 bins: 8 bins per thread (hist dead after v[u] load)
    int v[NKEY / 512];
    int sum = 0;
#pragma unroll
    for (int u = 0; u < NKEY / 512; ++u) {
        v[u] = hist[tid * (NKEY / 512) + u];
        sum += v[u];
    }
    sc[tid] = sum;
    __syncthreads();
    for (int off = 1; off < 512; off <<= 1) {
        int add = (tid >= off) ? sc[tid - off] : 0;
        __syncthreads();
        sc[tid] += add;
        __syncthreads();
    }
    int run = sc[tid] - sum;           // LOCAL exclusive offset within bucket
    // pair start offsets (absolute): bin p<<10 is the first bin of thread p*128
    if ((tid & 127) == 0) soff[bkt * 9 + (tid >> 7)] = bkt * CAPA + run;
    if (tid == 511) soff[bkt * 9 + 4] = bkt * CAPA + n;
    // overwrite own hist bins with local scatter cursors
#pragma unroll
    for (int u = 0; u < NKEY / 512; ++u) {
        hist[tid * (NKEY / 512) + u] = run;
        run += v[u];
    }
    __syncthreads();
    // scatter into LDS stage (local positions)
    for (int k = tid * 4; k < n4; k += 2048) {
        int4v e4 = *(const int4v*)(bs + k);
#pragma unroll
        for (int u = 0; u < 4; ++u) {
            int e = e4[u];
            int key = ((e >> 26) << 10) | ((e & 511) << 1) | ((e >> 25) & 1);
            int p = atomicAdd(&hist[key], 1);
            stage[p] = e;
        }
    }
    for (int k = n4 + tid; k < n; k += 512) {
        int e = bs[k];
        int key = ((e >> 26) << 10) | ((e & 511) << 1) | ((e >> 25) & 1);
        int p = atomicAdd(&hist[key], 1);
        stage[p] = e;
    }
    __syncthreads();
    // contiguous, vectorized write-out: full lines, temporally clustered
    int* ob = sortedB + (size_t)bkt * CAPA;
    for (int k = tid * 4; k < n4; k += 2048)
        *(int4v*)(ob + k) = *(const int4v*)(stage + k);
    for (int k = n4 + tid; k < n; k += 512)
        ob[k] = stage[k];
}

// ---------------- layer-1 pre-transform: x @ Wl1.T (10 -> 5), bf16x5 packed in 16 B ----------------
__global__ void __launch_bounds__(256) transform0(const float* __restrict__ x,
                                                  const float* __restrict__ Wl1,
                                                  uint4* __restrict__ t16) {
    int i = blockIdx.x * 256 + threadIdx.x;
    if (i >= NN) return;
    float xi[10];
#pragma unroll
    for (int k = 0; k < 10; ++k) xi[k] = x[i * 10 + k];
    float v[5];
#pragma unroll
    for (int j = 0; j < 5; ++j) {
        float a = 0.f;
#pragma unroll
        for (int k = 0; k < 10; ++k) a += xi[k] * Wl1[j * 10 + k];
        v[j] = a;
    }
    uint4 w;
    w.x = bfr(v[0]) | (bfr(v[1]) << 16);
    w.y = bfr(v[2]) | (bfr(v[3]) << 16);
    w.z = bfr(v[4]);
    w.w = 0;
    t16[i] = w;
}

// ---------------- core: process LDS-resident edge range, register acc, flush on dst change ----
__device__ __forceinline__ void process_range5_lds(const int* eds,
                                                   int k, const int ke,
                                                   const uint4* __restrict__ t16,
                                                   float* __restrict__ acc) {
    int cur = -1;
    float a0 = 0, a1 = 0, a2 = 0, a3 = 0, a4 = 0;
    auto flush = [&]() {
        if (cur >= 0) {
            float* p = &acc[cur * 5];
            atomicAdd(p + 0, a0); atomicAdd(p + 1, a1); atomicAdd(p + 2, a2);
            atomicAdd(p + 3, a3); atomicAdd(p + 4, a4);
        }
    };
    auto edge = [&](int e, uint4 w) {
        int d = e & 511;
        if (d != cur) { flush(); cur = d; a0 = a1 = a2 = a3 = a4 = 0.f; }
        a0 += bfl(w.x); a1 += bfh(w.x); a2 += bfl(w.y); a3 += bfh(w.y); a4 += bfl(w.z);
    };
    while (k < ke && (k & 3)) {
        int e = eds[k];
        edge(e, t16[e >> 9]);
        ++k;
    }
    for (; k + 3 < ke; k += 4) {
        int4v e4 = *(const int4v*)(eds + k);
        uint4 w0 = t16[e4.x >> 9];
        uint4 w1 = t16[e4.y >> 9];
        uint4 w2 = t16[e4.z >> 9];
        uint4 w3 = t16[e4.w >> 9];
        edge(e4.x, w0); edge(e4.y, w1); edge(e4.z, w2); edge(e4.w, w3);
    }
    for (; k < ke; ++k) {
        int e = eds[k];
        edge(e, t16[e >> 9]);
    }
    flush();
}

// ---------------- fused layer: DOUBLE-BUFFERED per-pair staging ----------------
// R14: occupancy 39.6->65% gave only -2% -> concurrency NOT the limit; per-CU
// serialization (divergent-gather TA path + per-phase stage-wait). This round
// isolates the stage-wait: issue pair p+1's loads into REGISTERS before
// processing pair p, land them into the alternate LDS buffer after (T14
// async-stage split). If dur is unchanged, the gather wall is confirmed.
// LDS 10+40=50 KB -> 3 blocks/CU (24 waves).
template <int FIN, int FNEXT>
__global__ void __launch_bounds__(512, 8) layer_fused(const int* __restrict__ soff,
                                                      const int* __restrict__ sorted,
                                                      const uint4* __restrict__ t16,
                                                      const float* __restrict__ hin,
                                                      const float* __restrict__ Wr,
                                                      const float* __restrict__ b,
                                                      const float* __restrict__ Wln,
                                                      const float* __restrict__ inv,
                                                      float* __restrict__ hout,
                                                      uint4* __restrict__ tn16,
                                                      float* __restrict__ tnP) {
    __shared__ float acc[BN * 5];      // 10 KB
    __shared__ int eds[2][PAIR_CAP];   // 40 KB
    const int bkt = blockIdx.x;
    const int tid = threadIdx.x;
    for (int k = tid; k < BN * 5; k += 512) acc[k] = 0.f;
    // prologue: stage pair 0 directly
    {
        const int beg = soff[bkt * 9 + 0];
        const int n0 = min(soff[bkt * 9 + 1] - beg, PAIR_CAP);
        for (int k = tid; k < n0; k += 512)
            eds[0][k] = __builtin_nontemporal_load(sorted + beg + k);
    }
    __syncthreads();
#pragma unroll
    for (int p = 0; p < 4; ++p) {
        const int cur = p & 1;
        const int n = min(soff[bkt * 9 + p + 1] - soff[bkt * 9 + p], PAIR_CAP);
        // async-stage split: issue next pair's loads into registers NOW
        int r[10];
        int nn = 0, begn = 0;
        if (p < 3) {
            begn = soff[bkt * 9 + p + 1];
            nn = min(soff[bkt * 9 + p + 2] - begn, PAIR_CAP);
#pragma unroll
            for (int j = 0; j < 10; ++j) {
                int k = tid + j * 512;
                if (k < nn) r[j] = __builtin_nontemporal_load(sorted + begn + k);
            }
        }
        // process current pair from LDS while the loads are in flight
        const int c = (n + 511) >> 9;
        const int k0 = tid * c;
        const int ke = min(k0 + c, n);
        if (k0 < ke) process_range5_lds(&eds[cur][0], k0, ke, t16, acc);
        // land the staged values into the other buffer
        if (p < 3) {
#pragma unroll
            for (int j = 0; j < 10; ++j) {
                int k = tid + j * 512;
                if (k < nn) eds[cur ^ 1][k] = r[j];
            }
        }
        __syncthreads();
    }

    int node = bkt * BN + tid;
    if (node >= NN) return;
    float iv = inv[node];
    float vin[FIN];
#pragma unroll
    for (int kk = 0; kk < FIN; ++kk) vin[kk] = hin[(size_t)node * FIN + kk];
    float ho[5];
#pragma unroll
    for (int jo = 0; jo < 5; ++jo) {
        float v = acc[tid * 5 + jo] * iv + b[jo];
#pragma unroll
        for (int kk = 0; kk < FIN; ++kk) v += vin[kk] * Wr[jo * FIN + kk];
        v = fmaxf(v, 0.f);
        hout[(size_t)node * 5 + jo] = v;
        ho[jo] = v;
    }
    if constexpr (FNEXT == 5) {
        float tv[5];
#pragma unroll
        for (int j2 = 0; j2 < 5; ++j2) {
            float v = 0.f;
#pragma unroll
            for (int jo = 0; jo < 5; ++jo) v += ho[jo] * Wln[j2 * 5 + jo];
            tv[j2] = v;
        }
        uint4 w;
        w.x = bfr(tv[0]) | (bfr(tv[1]) << 16);
        w.y = bfr(tv[2]) | (bfr(tv[3]) << 16);
        w.z = bfr(tv[4]);
        w.w = 0;
        tn16[node] = w;
    } else {  // FNEXT == 1: fp32 stride-1 plane for the final layer
        float v = 0.f;
#pragma unroll
        for (int jo = 0; jo < 5; ++jo) v += ho[jo] * Wln[jo];
        tnP[node] = v;
    }
}

// ---------------- final layer (5 -> 1): per-pair LDS staging (R14 pattern) ----------------
// Was full-bucket 68 KB -> 1-2 blocks/CU; now 22 KB -> 4 blocks/CU.
__global__ void __launch_bounds__(512, 8) final_layer(const int* __restrict__ soff,
                                                      const int* __restrict__ sorted,
                                                      const float* __restrict__ t,
                                                      const float* __restrict__ hin,
                                                      const float* __restrict__ Wr,
                                                      const float* __restrict__ b,
                                                      const float* __restrict__ inv,
                                                      float* __restrict__ out) {
    __shared__ float acc[BN];       // 2 KB
    __shared__ int eds[PAIR_CAP];   // 20 KB
    const int bkt = blockIdx.x;
    const int tid = threadIdx.x;
    acc[tid] = 0.f;  // BN==512
#pragma unroll
    for (int p = 0; p < 4; ++p) {
        const int beg = soff[bkt * 9 + p];
        const int n = min(soff[bkt * 9 + p + 1] - beg, PAIR_CAP);
        for (int k = tid; k < n; k += 512)
            eds[k] = __builtin_nontemporal_load(sorted + beg + k);
        __syncthreads();
        const int c = (n + 511) >> 9;
        int kk = tid * c;
        const int ke = min(kk + c, n);
        int cur = -1;
        float a0 = 0.f;
        auto flush = [&]() { if (cur >= 0) atomicAdd(&acc[cur], a0); };
        auto edge = [&](int e, float q) {
            int d = e & 511;
            if (d != cur) { flush(); cur = d; a0 = 0.f; }
            a0 += q;
        };
        while (kk < ke && (kk & 3)) { int e = eds[kk]; edge(e, t[e >> 9]); ++kk; }
        for (; kk + 3 < ke; kk += 4) {
            int4v e4 = *(const int4v*)(eds + kk);
            float q0 = t[e4.x >> 9], q1 = t[e4.y >> 9], q2 = t[e4.z >> 9], q3 = t[e4.w >> 9];
            edge(e4.x, q0); edge(e4.y, q1); edge(e4.z, q2); edge(e4.w, q3);
        }
        for (; kk < ke; ++kk) { int e = eds[kk]; edge(e, t[e >> 9]); }
        flush();
        __syncthreads();
    }
    int node = bkt * BN + tid;
    if (node >= NN) return;
    float v = acc[tid] * inv[node] + b[0];
#pragma unroll
    for (int kq = 0; kq < 5; ++kq) v += hin[(size_t)node * 5 + kq] * Wr[kq];
    out[node] = v;
}

extern "C" void kernel_launch(void* const* d_in, const int* in_sizes, int n_in,
                              void* d_out, int out_size, void* d_ws, size_t ws_size,
                              hipStream_t stream) {
    (void)in_sizes; (void)n_in; (void)out_size; (void)ws_size;
    const float* x    = (const float*)d_in[0];
    const int*   ei   = (const int*)d_in[1];
    const float* Wl1  = (const float*)d_in[2];
    const float* Wr1  = (const float*)d_in[3];
    const float* b1   = (const float*)d_in[4];
    const float* Wlm  = (const float*)d_in[5];
    const float* Wrm  = (const float*)d_in[6];
    const float* bm   = (const float*)d_in[7];
    const float* Wl10 = (const float*)d_in[8];
    const float* Wr10 = (const float*)d_in[9];
    const float* b10  = (const float*)d_in[10];
    float* out = (float*)d_out;

    const int* src = ei;
    const int* dst = ei + NE;

    // workspace layout (4-byte units)
    int* wsI = (int*)d_ws;
    int*   gcnt    = wsI;                         // 977 -> pad 1024
    int*   soff    = wsI + 1024;                  // 977*9 used at stride 9 (5 live)
    int*   sortedB = wsI + 10240;                 // 977*17408 = 17,007,616
    float* inv     = (float*)(wsI + 17017856);    // 500,224
    int*   storeA  = wsI + 20019200;              // 17,007,616 (dead after passB)
    // feature tables alias the dead storeA region (9.5M ints < 17M):
    uint4* tA = (uint4*)(wsI + 20019200);         // NN uint4 = 2,000,000 ints (16B-aligned)
    uint4* tB = (uint4*)(wsI + 22019200);         // 2,000,000 ints
    float* tP = (float*)(wsI + 24019200);         // 500,224 (final-layer fp32 plane)
    float* hA = (float*)(wsI + 24519424);         // 2,500,608
    float* hB = (float*)(wsI + 27020032);         // 2,500,608 -> end 29,520,640

    dim3 gb(NBUCK);
    dim3 tb(512);

    // ---- build: two-pass (dst-bucket, then (pair,dst,parity) sort) ----
    hipMemsetAsync(gcnt, 0, 1024 * sizeof(int), stream);
    passA<<<dim3(NTILE_A), dim3(1024), 0, stream>>>(src, dst, gcnt, storeA);
    passB<<<gb, tb, 0, stream>>>(gcnt, storeA, sortedB, inv, soff);

    // ---- layer 1 (10 -> 5) ----  (transform0 overwrites storeA AFTER passB)
    transform0<<<dim3(NB_NODE), dim3(256), 0, stream>>>(x, Wl1, tA);
    layer_fused<10, 5><<<gb, tb, 0, stream>>>(soff, sortedB, tA,
                                              x, Wr1, b1, Wlm, inv, hA, tB, nullptr);

    // ---- middle layers 0..6 (5 -> 5) ----
    const uint4* tcur = tB; uint4* tnxt = tA;
    const float* hcur = hA; float* hnext = hB;
    for (int mi = 0; mi < 7; ++mi) {
        layer_fused<5, 5><<<gb, tb, 0, stream>>>(soff, sortedB, tcur,
                                                 hcur, Wrm + mi * 25, bm + mi * 5,
                                                 Wlm + (mi + 1) * 25, inv, hnext,
                                                 tnxt, nullptr);
        const uint4* tt = tcur; tcur = tnxt; tnxt = (uint4*)tt;
        const float* th = hcur; hcur = hnext; hnext = (float*)th;
    }
    // ---- middle layer 7: next pre-transform is final (5 -> 1) -> fp32 plane ----
    layer_fused<5, 1><<<gb, tb, 0, stream>>>(soff, sortedB, tcur,
                                             hcur, Wrm + 7 * 25, bm + 7 * 5,
                                             Wl10, inv, hnext, nullptr, tP);
    // ---- final layer (5 -> 1), no relu ----
    final_layer<<<gb, tb, 0, stream>>>(soff, sortedB, tP, hnext, Wr10, b10, inv, out);
}

// Round 17
// 1558.747 us; speedup vs baseline: 1.0198x; 1.0198x over previous
//
#include <hip/hip_runtime.h>

constexpr int NN = 500000;
constexpr int NE = 16000000;
constexpr int BN = 512;                       // dst nodes per bucket
constexpr int NBUCK = (NN + BN - 1) / BN;     // 977
constexpr int NSLICE = 8;                     // src slices of 65536 nodes
constexpr int NKEY = NSLICE * BN;             // 4096 sort bins per bucket
constexpr int CAPA = 17408;                   // per-bucket cap: mean 16384, +8 sigma
constexpr int PAIR_CAP = 5120;                // per-pair cap: mean 4094, +16 sigma
constexpr int TILE_A = 16384;                 // edges per pass-A tile (LDS-staged)
constexpr int NTILE_A = (NE + TILE_A - 1) / TILE_A; // 977
constexpr int NB_NODE = (NN + 255) / 256;     // 1954

typedef int int4v __attribute__((ext_vector_type(4)));

// ---------------- bf16 helpers ----------------
__device__ __forceinline__ unsigned bfr(float x) {   // fp32 -> bf16 bits (RNE)
    unsigned u = __float_as_uint(x);
    u += 0x7fffu + ((u >> 16) & 1u);
    return u >> 16;
}
__device__ __forceinline__ float bfl(unsigned u) { return __uint_as_float(u << 16); }
__device__ __forceinline__ float bfh(unsigned u) { return __uint_as_float(u & 0xffff0000u); }

// ---------------- pass A: LDS counting sort per tile, coalesced bucket write-out ----
// R1: scattered 4B stores -> 392 MB WRITE_SIZE. R4: fixed (passA out of top-5).
__global__ void __launch_bounds__(1024, 8) passA(const int* __restrict__ src,
                                                 const int* __restrict__ dst,
                                                 int* __restrict__ gcnt,
                                                 int* __restrict__ storeA) {
    __shared__ int hist[1024];    // per-bucket count (977 used)
    __shared__ int lbase[1024];   // local exclusive scan (bucket start in stage)
    __shared__ int lcur[1024];    // local scatter cursor
    __shared__ int gbase[1024];   // absolute base in storeA
    __shared__ int stage[TILE_A]; // 64 KB sorted tile
    const int tid = threadIdx.x;
    const int base = blockIdx.x * TILE_A;
    const int nt = min(TILE_A, NE - base);
    hist[tid] = 0;
    __syncthreads();
    for (int i = tid; i < nt; i += 1024)
        atomicAdd(&hist[dst[base + i] >> 9], 1);
    __syncthreads();
    const int cnt = hist[tid];
    lbase[tid] = cnt;
    __syncthreads();
    // inclusive Hillis-Steele scan over 1024 bins
    for (int off = 1; off < 1024; off <<= 1) {
        int add = (tid >= off) ? lbase[tid - off] : 0;
        __syncthreads();
        lbase[tid] += add;
        __syncthreads();
    }
    const int lb = lbase[tid] - cnt;   // exclusive
    lcur[tid] = lb;
    if (tid < NBUCK && cnt > 0) {
        int g = atomicAdd(&gcnt[tid], cnt);
        gbase[tid] = tid * CAPA + g;
    }
    __syncthreads();
    lbase[tid] = lb;                   // publish exclusive base for write-out
    // scatter tile into LDS in bucket-sorted order
    for (int i = tid; i < nt; i += 1024) {
        int d = dst[base + i];
        int s = src[base + i];         // tile window L2-hot on re-read
        int p = atomicAdd(&lcur[d >> 9], 1);
        stage[p] = (s << 9) | (d & 511);
    }
    __syncthreads();
    // coalesced write-out: one bucket per wave iteration
    const int wid = tid >> 6, lane = tid & 63;
    for (int b = wid; b < NBUCK; b += 16) {
        int c = hist[b];
        if (c == 0) continue;
        int l0 = lbase[b];
        int g0 = gbase[b];
        int wl = min(c, (b + 1) * CAPA - g0);  // statistically never clips
        for (int j = lane; j < wl; j += 64)
            storeA[g0 + j] = stage[l0 + j];
    }
}

// ---------------- pass B: per-bucket sort by (PAIR, dst, slice-parity) ----------------
// R11 confirmed: (pair,dst,parity) key (~8-edge runs) + pair-phases = best.
// key(e): pair = e>>26, parity = (e>>25)&1, dst = e&511.
__global__ void __launch_bounds__(512) passB(const int* __restrict__ gcnt,
                                             const int* __restrict__ storeA,
                                             int* __restrict__ sortedB,
                                             float* __restrict__ inv,
                                             int* __restrict__ soff) {
    __shared__ int hist[NKEY];    // 16 KB: counts, then (after scan) scatter cursors
    __shared__ int sc[512];       // 2 KB
    __shared__ int stage[CAPA];   // 68 KB sorted bucket
    const int bkt = blockIdx.x;
    const int tid = threadIdx.x;
#pragma unroll
    for (int u = 0; u < NKEY / 512; ++u) hist[tid + u * 512] = 0;
    __syncthreads();
    const int n = min(gcnt[bkt], CAPA);
    const int* bs = storeA + (size_t)bkt * CAPA;
    // histogram (dwordx4 reads; bs is 16B-aligned, tail scalar)
    const int n4 = n & ~3;
    for (int k = tid * 4; k < n4; k += 2048) {
        int4v e4 = *(const int4v*)(bs + k);
#pragma unroll
        for (int u = 0; u < 4; ++u) {
            int e = e4[u];
            int key = ((e >> 26) << 10) | ((e & 511) << 1) | ((e >> 25) & 1);
            atomicAdd(&hist[key], 1);
        }
    }
    for (int k = n4 + tid; k < n; k += 512) {
        int e = bs[k];
        int key = ((e >> 26) << 10) | ((e & 511) << 1) | ((e >> 25) & 1);
        atomicAdd(&hist[key], 1);
    }
    __syncthreads();
    // inv[] from per-dst counts (sum over 4 pairs x 2 parities)
    {
        int node = bkt * BN + tid;
        if (node < NN) {
            int c = 0;
#pragma unroll
            for (int p = 0; p < 4; ++p)
#pragma unroll
                for (int q = 0; q < 2; ++q)
                    c += hist[(p << 10) | (tid << 1) | q];
            inv[node] = 1.0f / fmaxf((float)c, 1.0f);
        }
    }
    // exclusive scan of 4096 bins: 8 bins per thread (hist dead after v[u] load)
    int v[NKEY / 512];
    int sum = 0;
#pragma unroll
    for (int u = 0; u < NKEY / 512; ++u) {
        v[u] = hist[tid * (NKEY / 512) + u];
        sum += v[u];
    }
    sc[tid] = sum;
    __syncthreads();
    for (int off = 1; off < 512; off <<= 1) {
        int add = (tid >= off) ? sc[tid - off] : 0;
        __syncthreads();
        sc[tid] += add;
        __syncthreads();
    }
    int run = sc[tid] - sum;           // LOCAL exclusive offset within bucket
    // pair start offsets (absolute): bin p<<10 is the first bin of thread p*128
    if ((tid & 127) == 0) soff[bkt * 9 + (tid >> 7)] = bkt * CAPA + run;
    if (tid == 511) soff[bkt * 9 + 4] = bkt * CAPA + n;
    // overwrite own hist bins with local scatter cursors
#pragma unroll
    for (int u = 0; u < NKEY / 512; ++u) {
        hist[tid * (NKEY / 512) + u] = run;
        run += v[u];
    }
    __syncthreads();
    // scatter into LDS stage (local positions)
    for (int k = tid * 4; k < n4; k += 2048) {
        int4v e4 = *(const int4v*)(bs + k);
#pragma unroll
        for (int u = 0; u < 4; ++u) {
            int e = e4[u];
            int key = ((e >> 26) << 10) | ((e & 511) << 1) | ((e >> 25) & 1);
            int p = atomicAdd(&hist[key], 1);
            stage[p] = e;
        }
    }
    for (int k = n4 + tid; k < n; k += 512) {
        int e = bs[k];
        int key = ((e >> 26) << 10) | ((e & 511) << 1) | ((e >> 25) & 1);
        int p = atomicAdd(&hist[key], 1);
        stage[p] = e;
    }
    __syncthreads();
    // contiguous, vectorized write-out: full lines, temporally clustered
    int* ob = sortedB + (size_t)bkt * CAPA;
    for (int k = tid * 4; k < n4; k += 2048)
        *(int4v*)(ob + k) = *(const int4v*)(stage + k);
    for (int k = n4 + tid; k < n; k += 512)
        ob[k] = stage[k];
}

// ---------------- layer-1 pre-transform: x @ Wl1.T (10 -> 5), bf16x5 packed in 16 B ----------------
__global__ void __launch_bounds__(256) transform0(const float* __restrict__ x,
                                                  const float* __restrict__ Wl1,
                                                  uint4* __restrict__ t16) {
    int i = blockIdx.x * 256 + threadIdx.x;
    if (i >= NN) return;
    float xi[10];
#pragma unroll
    for (int k = 0; k < 10; ++k) xi[k] = x[i * 10 + k];
    float v[5];
#pragma unroll
    for (int j = 0; j < 5; ++j) {
        float a = 0.f;
#pragma unroll
        for (int k = 0; k < 10; ++k) a += xi[k] * Wl1[j * 10 + k];
        v[j] = a;
    }
    uint4 w;
    w.x = bfr(v[0]) | (bfr(v[1]) << 16);
    w.y = bfr(v[2]) | (bfr(v[3]) << 16);
    w.z = bfr(v[4]);
    w.w = 0;
    t16[i] = w;
}

// ---------------- core: process LDS-resident edge range, register acc, flush on dst change ----
// 4-wide loop (R11: 8-wide neutral at ~8-edge runs; 4-wide keeps VGPR <= 64
// so 8 waves/EU fits). Edges from LDS (~120cy), gathers from L2 (~200cy).
__device__ __forceinline__ void process_range5_lds(const int* eds,
                                                   int k, const int ke,
                                                   const uint4* __restrict__ t16,
                                                   float* __restrict__ acc) {
    int cur = -1;
    float a0 = 0, a1 = 0, a2 = 0, a3 = 0, a4 = 0;
    auto flush = [&]() {
        if (cur >= 0) {
            float* p = &acc[cur * 5];
            atomicAdd(p + 0, a0); atomicAdd(p + 1, a1); atomicAdd(p + 2, a2);
            atomicAdd(p + 3, a3); atomicAdd(p + 4, a4);
        }
    };
    auto edge = [&](int e, uint4 w) {
        int d = e & 511;
        if (d != cur) { flush(); cur = d; a0 = a1 = a2 = a3 = a4 = 0.f; }
        a0 += bfl(w.x); a1 += bfh(w.x); a2 += bfl(w.y); a3 += bfh(w.y); a4 += bfl(w.z);
    };
    while (k < ke && (k & 3)) {
        int e = eds[k];
        edge(e, t16[e >> 9]);
        ++k;
    }
    for (; k + 3 < ke; k += 4) {
        int4v e4 = *(const int4v*)(eds + k);
        uint4 w0 = t16[e4.x >> 9];
        uint4 w1 = t16[e4.y >> 9];
        uint4 w2 = t16[e4.z >> 9];
        uint4 w3 = t16[e4.w >> 9];
        edge(e4.x, w0); edge(e4.y, w1); edge(e4.z, w2); edge(e4.w, w3);
    }
    for (; k < ke; ++k) {
        int e = eds[k];
        edge(e, t16[e >> 9]);
    }
    flush();
}

// ---------------- fused layer: per-PAIR LDS staging (R14 config — best measured) ----
// Structural-wall record: R12 full-bucket(2blk/CU)=137, R14 per-pair(4blk)=134,
// R16 per-pair+dbuf(3blk)=137 -> occupancy/pipelining don't move it. The sweep
// is at the divergent-gather request-rate wall (~62.5K lane-gathers/CU @
// ~4-5cy each ~ 110-125us). Keep the simplest/best variant.
template <int FIN, int FNEXT>
__global__ void __launch_bounds__(512, 8) layer_fused(const int* __restrict__ soff,
                                                      const int* __restrict__ sorted,
                                                      const uint4* __restrict__ t16,
                                                      const float* __restrict__ hin,
                                                      const float* __restrict__ Wr,
                                                      const float* __restrict__ b,
                                                      const float* __restrict__ Wln,
                                                      const float* __restrict__ inv,
                                                      float* __restrict__ hout,
                                                      uint4* __restrict__ tn16,
                                                      float* __restrict__ tnP) {
    __shared__ float acc[BN * 5];   // 10 KB
    __shared__ int eds[PAIR_CAP];   // 20 KB
    const int bkt = blockIdx.x;
    const int tid = threadIdx.x;
    for (int k = tid; k < BN * 5; k += 512) acc[k] = 0.f;
#pragma unroll
    for (int p = 0; p < 4; ++p) {
        const int beg = soff[bkt * 9 + p];
        const int n = min(soff[bkt * 9 + p + 1] - beg, PAIR_CAP);
        // stage this pair's edges (coalesced dword stream; beg not 16B-aligned)
#pragma unroll 4
        for (int k = tid; k < n; k += 512)
            eds[k] = __builtin_nontemporal_load(sorted + beg + k);
        __syncthreads();
        const int c = (n + 511) >> 9;
        const int k = tid * c;
        const int ke = min(k + c, n);
        if (k < ke) process_range5_lds(eds, k, ke, t16, acc);
        __syncthreads();
    }

    int node = bkt * BN + tid;
    if (node >= NN) return;
    float iv = inv[node];
    float vin[FIN];
#pragma unroll
    for (int kk = 0; kk < FIN; ++kk) vin[kk] = hin[(size_t)node * FIN + kk];
    float ho[5];
#pragma unroll
    for (int jo = 0; jo < 5; ++jo) {
        float v = acc[tid * 5 + jo] * iv + b[jo];
#pragma unroll
        for (int kk = 0; kk < FIN; ++kk) v += vin[kk] * Wr[jo * FIN + kk];
        v = fmaxf(v, 0.f);
        hout[(size_t)node * 5 + jo] = v;
        ho[jo] = v;
    }
    if constexpr (FNEXT == 5) {
        float tv[5];
#pragma unroll
        for (int j2 = 0; j2 < 5; ++j2) {
            float v = 0.f;
#pragma unroll
            for (int jo = 0; jo < 5; ++jo) v += ho[jo] * Wln[j2 * 5 + jo];
            tv[j2] = v;
        }
        uint4 w;
        w.x = bfr(tv[0]) | (bfr(tv[1]) << 16);
        w.y = bfr(tv[2]) | (bfr(tv[3]) << 16);
        w.z = bfr(tv[4]);
        w.w = 0;
        tn16[node] = w;
    } else {  // FNEXT == 1: fp32 stride-1 plane for the final layer
        float v = 0.f;
#pragma unroll
        for (int jo = 0; jo < 5; ++jo) v += ho[jo] * Wln[jo];
        tnP[node] = v;
    }
}

// ---------------- final layer (5 -> 1): per-pair LDS staging (kept from R16, ~neutral) ----
__global__ void __launch_bounds__(512, 8) final_layer(const int* __restrict__ soff,
                                                      const int* __restrict__ sorted,
                                                      const float* __restrict__ t,
                                                      const float* __restrict__ hin,
                                                      const float* __restrict__ Wr,
                                                      const float* __restrict__ b,
                                                      const float* __restrict__ inv,
                                                      float* __restrict__ out) {
    __shared__ float acc[BN];       // 2 KB
    __shared__ int eds[PAIR_CAP];   // 20 KB
    const int bkt = blockIdx.x;
    const int tid = threadIdx.x;
    acc[tid] = 0.f;  // BN==512
#pragma unroll
    for (int p = 0; p < 4; ++p) {
        const int beg = soff[bkt * 9 + p];
        const int n = min(soff[bkt * 9 + p + 1] - beg, PAIR_CAP);
        for (int k = tid; k < n; k += 512)
            eds[k] = __builtin_nontemporal_load(sorted + beg + k);
        __syncthreads();
        const int c = (n + 511) >> 9;
        int kk = tid * c;
        const int ke = min(kk + c, n);
        int cur = -1;
        float a0 = 0.f;
        auto flush = [&]() { if (cur >= 0) atomicAdd(&acc[cur], a0); };
        auto edge = [&](int e, float q) {
            int d = e & 511;
            if (d != cur) { flush(); cur = d; a0 = 0.f; }
            a0 += q;
        };
        while (kk < ke && (kk & 3)) { int e = eds[kk]; edge(e, t[e >> 9]); ++kk; }
        for (; kk + 3 < ke; kk += 4) {
            int4v e4 = *(const int4v*)(eds + kk);
            float q0 = t[e4.x >> 9], q1 = t[e4.y >> 9], q2 = t[e4.z >> 9], q3 = t[e4.w >> 9];
            edge(e4.x, q0); edge(e4.y, q1); edge(e4.z, q2); edge(e4.w, q3);
        }
        for (; kk < ke; ++kk) { int e = eds[kk]; edge(e, t[e >> 9]); }
        flush();
        __syncthreads();
    }
    int node = bkt * BN + tid;
    if (node >= NN) return;
    float v = acc[tid] * inv[node] + b[0];
#pragma unroll
    for (int kq = 0; kq < 5; ++kq) v += hin[(size_t)node * 5 + kq] * Wr[kq];
    out[node] = v;
}

extern "C" void kernel_launch(void* const* d_in, const int* in_sizes, int n_in,
                              void* d_out, int out_size, void* d_ws, size_t ws_size,
                              hipStream_t stream) {
    (void)in_sizes; (void)n_in; (void)out_size; (void)ws_size;
    const float* x    = (const float*)d_in[0];
    const int*   ei   = (const int*)d_in[1];
    const float* Wl1  = (const float*)d_in[2];
    const float* Wr1  = (const float*)d_in[3];
    const float* b1   = (const float*)d_in[4];
    const float* Wlm  = (const float*)d_in[5];
    const float* Wrm  = (const float*)d_in[6];
    const float* bm   = (const float*)d_in[7];
    const float* Wl10 = (const float*)d_in[8];
    const float* Wr10 = (const float*)d_in[9];
    const float* b10  = (const float*)d_in[10];
    float* out = (float*)d_out;

    const int* src = ei;
    const int* dst = ei + NE;

    // workspace layout (4-byte units)
    int* wsI = (int*)d_ws;
    int*   gcnt    = wsI;                         // 977 -> pad 1024
    int*   soff    = wsI + 1024;                  // 977*9 used at stride 9 (5 live)
    int*   sortedB = wsI + 10240;                 // 977*17408 = 17,007,616
    float* inv     = (float*)(wsI + 17017856);    // 500,224
    int*   storeA  = wsI + 20019200;              // 17,007,616 (dead after passB)
    // feature tables alias the dead storeA region (9.5M ints < 17M):
    uint4* tA = (uint4*)(wsI + 20019200);         // NN uint4 = 2,000,000 ints (16B-aligned)
    uint4* tB = (uint4*)(wsI + 22019200);         // 2,000,000 ints
    float* tP = (float*)(wsI + 24019200);         // 500,224 (final-layer fp32 plane)
    float* hA = (float*)(wsI + 24519424);         // 2,500,608
    float* hB = (float*)(wsI + 27020032);         // 2,500,608 -> end 29,520,640

    dim3 gb(NBUCK);
    dim3 tb(512);

    // ---- build: two-pass (dst-bucket, then (pair,dst,parity) sort) ----
    hipMemsetAsync(gcnt, 0, 1024 * sizeof(int), stream);
    passA<<<dim3(NTILE_A), dim3(1024), 0, stream>>>(src, dst, gcnt, storeA);
    passB<<<gb, tb, 0, stream>>>(gcnt, storeA, sortedB, inv, soff);

    // ---- layer 1 (10 -> 5) ----  (transform0 overwrites storeA AFTER passB)
    transform0<<<dim3(NB_NODE), dim3(256), 0, stream>>>(x, Wl1, tA);
    layer_fused<10, 5><<<gb, tb, 0, stream>>>(soff, sortedB, tA,
                                              x, Wr1, b1, Wlm, inv, hA, tB, nullptr);

    // ---- middle layers 0..6 (5 -> 5) ----
    const uint4* tcur = tB; uint4* tnxt = tA;
    const float* hcur = hA; float* hnext = hB;
    for (int mi = 0; mi < 7; ++mi) {
        layer_fused<5, 5><<<gb, tb, 0, stream>>>(soff, sortedB, tcur,
                                                 hcur, Wrm + mi * 25, bm + mi * 5,
                                                 Wlm + (mi + 1) * 25, inv, hnext,
                                                 tnxt, nullptr);
        const uint4* tt = tcur; tcur = tnxt; tnxt = (uint4*)tt;
        const float* th = hcur; hcur = hnext; hnext = (float*)th;
    }
    // ---- middle layer 7: next pre-transform is final (5 -> 1) -> fp32 plane ----
    layer_fused<5, 1><<<gb, tb, 0, stream>>>(soff, sortedB, tcur,
                                             hcur, Wrm + 7 * 25, bm + 7 * 5,
                                             Wl10, inv, hnext, nullptr, tP);
    // ---- final layer (5 -> 1), no relu ----
    final_layer<<<gb, tb, 0, stream>>>(soff, sortedB, tP, hnext, Wr10, b10, inv, out);
}